// Round 3
// baseline (302.019 us; speedup 1.0000x reference)
//
#include <hip/hip_runtime.h>
#include <hip/hip_bf16.h>

#define B_N 16384
#define D_K 128

typedef __bf16 bf16x8 __attribute__((ext_vector_type(8)));
typedef float f32x4 __attribute__((ext_vector_type(4)));
typedef float f32x2 __attribute__((ext_vector_type(2)));

#if defined(__has_builtin)
#if __has_builtin(__builtin_amdgcn_exp2f)
#define EXP2F(x) __builtin_amdgcn_exp2f(x)
#else
#define EXP2F(x) exp2f(x)
#endif
#else
#define EXP2F(x) exp2f(x)
#endif

__device__ __forceinline__ void gload_lds16(const void* g, void* l) {
  __builtin_amdgcn_global_load_lds(
      (const __attribute__((address_space(1))) unsigned int*)g,
      (__attribute__((address_space(3))) unsigned int*)l, 16, 0, 0);
}

// ---------------- kernel 1: normalize rows, prescale by sqrt(1/(T*ln2)), build col weights
__global__ __launch_bounds__(256) void prep_kernel(
    const float* __restrict__ E, const int* __restrict__ labels,
    const int* __restrict__ mask, __hip_bfloat16* __restrict__ Ebf,
    float2* __restrict__ W)
{
  int tid = threadIdx.x;
  int gtid = blockIdx.x * 256 + tid;
  if (gtid < B_N) {
    int lb = labels[gtid];
    float wm = (mask[gtid] != 0) ? 1.0f : 0.0f;
    W[gtid] = make_float2((lb == 0) ? wm : 0.0f, wm);
  }
  int lane = tid & 63;
  int wid = gtid >> 6;  // 4096 waves total (grid 1024 x 256) -> 4 rows/wave
  const float2* E2 = (const float2*)E;
  __hip_bfloat162* O2 = (__hip_bfloat162*)Ebf;
  for (int row = wid; row < B_N; row += 4096) {
    float2 v = E2[row * 64 + lane];
    float ss = v.x * v.x + v.y * v.y;
    #pragma unroll
    for (int m = 1; m < 64; m <<= 1) ss += __shfl_xor(ss, m);
    // sqrt(14.426950408889634) = sqrt(1/(0.1*ln2)); folded into both operands
    float sc = 3.7982826f / fmaxf(sqrtf(ss), 1e-12f);
    __hip_bfloat162 h;
    h.x = __float2bfloat16(v.x * sc);
    h.y = __float2bfloat16(v.y * sc);
    O2[row * 64 + lane] = h;
  }
}

// ---------------- kernel 2: fused Gram + exp + masked row-sum
// 64-col double-buffered tiles, T3 2-phase schedule (stage next -> compute cur -> vmcnt(0) -> barrier)
template<bool DIAG>
__device__ __forceinline__ void tile_compute(
    const char* lds, const bf16x8 a[4][4],
    const float2* __restrict__ W, int C0, int lane, int WR0,
    f32x2 acc[4][4])
{
  const int l15 = lane & 15, lg = lane >> 4, l7 = lane & 7;
  #pragma unroll
  for (int nf = 0; nf < 4; ++nf) {   // 4 x 16 = 64 cols
    int col = nf * 16 + l15;
    int colg = C0 + col;
    f32x2 wv = *(const f32x2*)&W[colg];  // (label0 weight, total weight)
    bf16x8 b[4];
    #pragma unroll
    for (int kk = 0; kk < 4; ++kk) {
      // XOR-swizzled chunk address (matches swizzled staging source)
      int addr = col * 256 + (((kk * 4 + lg) ^ l7) << 4);
      b[kk] = *(const bf16x8*)(lds + addr);
    }
    #pragma unroll
    for (int mf = 0; mf < 4; ++mf) {
      f32x4 c = {0.f, 0.f, 0.f, 0.f};
      #pragma unroll
      for (int kk = 0; kk < 4; ++kk)
        c = __builtin_amdgcn_mfma_f32_16x16x32_bf16(a[mf][kk], b[kk], c, 0, 0, 0);
      #pragma unroll
      for (int r = 0; r < 4; ++r) {
        float p = EXP2F(c[r]);       // exp(sim/T), scale folded into operands
        if (DIAG) {
          int rowg = WR0 + mf * 16 + lg * 4 + r;  // verified C/D layout
          p = (rowg == colg) ? 0.0f : p;
        }
        // packed FMA: one v_pk_fma_f32 updates (label-0 sum, total sum)
        acc[mf][r] += wv * p;
      }
    }
  }
}

// launch_bounds 2nd arg = min waves/EU; budget is the UNIFIED VGPR+AGPR file (512/waves).
// (256,4)=128 budget: 64V+64A + catastrophic spill (round 1, FETCH 24MB->1.8GB).
// (256,2)=256 budget: 128V + AGPR accs -> only 2 waves/SIMD, occupancy capped at 25%.
// (256,3)=170 budget: live state ~145 regs -> fits, 3 blocks/CU, 37.5% occupancy.
__global__ __launch_bounds__(256, 3) void gemm_kernel(
    const __hip_bfloat16* __restrict__ Ebf, const float2* __restrict__ W,
    float2* __restrict__ SW, int colsPerSplit)
{
  __shared__ alignas(16) char tile[32768];  // 2 buffers x (64 cols x 128 K x bf16)
  const int tid = threadIdx.x;
  const int lane = tid & 63;
  const int w = tid >> 6;
  const int R0 = blockIdx.x * 256;
  const int WR0 = R0 + w * 64;   // 64 rows per wave
  const int l15 = lane & 15, lg = lane >> 4;

  // A fragments: 4 m-frags x 4 k-steps, held in VGPRs for the whole col loop
  bf16x8 a[4][4];
  #pragma unroll
  for (int mf = 0; mf < 4; ++mf) {
    #pragma unroll
    for (int kk = 0; kk < 4; ++kk) {
      int row = WR0 + mf * 16 + l15;
      a[mf][kk] = *(const bf16x8*)(Ebf + (size_t)row * D_K + kk * 32 + lg * 8);
    }
  }

  // staging offsets: linear LDS dest, swizzle applied to the GLOBAL source (m173 pattern)
  int goff[4], loff[4];
  #pragma unroll
  for (int i = 0; i < 4; ++i) {
    int q = i * 4 + w;            // 1KB chunk-group id 0..15 (16KB tile)
    int col = q * 4 + lg;         // tile-local col this lane feeds (0..63)
    int c = l15 ^ (col & 7);      // inverse-swizzled 16B chunk within the 256B row
    goff[i] = col * D_K + c * 8;  // bf16 elements
    loff[i] = q * 1024;           // wave-uniform LDS base (bytes)
  }

  f32x2 acc[4][4] = {};
  const int colBase = blockIdx.y * colsPerSplit;
  const int nt = colsPerSplit >> 6;

  // prologue: stage tile 0, drain, rendezvous
  {
    const __hip_bfloat16* src = Ebf + (size_t)colBase * D_K;
    #pragma unroll
    for (int i = 0; i < 4; ++i) gload_lds16(src + goff[i], tile + loff[i]);
    asm volatile("s_waitcnt vmcnt(0)" ::: "memory");
    __builtin_amdgcn_s_barrier();
  }

  int cur = 0;
  for (int t = 0; t < nt; ++t) {
    if (t + 1 < nt) {   // block-uniform branch: prefetch next tile into the other buffer
      const __hip_bfloat16* src = Ebf + (size_t)(colBase + (t + 1) * 64) * D_K;
      char* dst = tile + ((cur ^ 1) << 14);
      #pragma unroll
      for (int i = 0; i < 4; ++i) gload_lds16(src + goff[i], dst + loff[i]);
    }
    const int C0 = colBase + t * 64;
    const char* lds = tile + (cur << 14);
    const bool diag = (C0 < R0 + 256) && (C0 + 64 > R0);
    if (diag) tile_compute<true >(lds, a, W, C0, lane, WR0, acc);
    else      tile_compute<false>(lds, a, W, C0, lane, WR0, acc);
    // loads for tile t+1 were issued BEFORE compute: this drain is latency-hidden
    asm volatile("s_waitcnt vmcnt(0)" ::: "memory");
    __builtin_amdgcn_s_barrier();
    cur ^= 1;
  }

  // reduce the 16 lanes (same row-group, different col subsets), then store
  #pragma unroll
  for (int mf = 0; mf < 4; ++mf) {
    #pragma unroll
    for (int r = 0; r < 4; ++r) {
      float s0 = acc[mf][r].x, tt = acc[mf][r].y;
      #pragma unroll
      for (int m = 1; m < 16; m <<= 1) {
        s0 += __shfl_xor(s0, m);
        tt += __shfl_xor(tt, m);
      }
      if (l15 == 0) {
        int rowg = WR0 + mf * 16 + lg * 4 + r;
        SW[(size_t)blockIdx.y * B_N + rowg] = make_float2(s0, tt);
      }
    }
  }
}

// ---------------- kernel 3a: per-row loss, 64 blocks, deterministic partials
__global__ __launch_bounds__(256) void loss_part(
    const int* __restrict__ labels, const int* __restrict__ mask,
    const float2* __restrict__ SW, int NS, float2* __restrict__ partial)
{
  __shared__ int sc0[4], sc1[4];
  __shared__ float st[4], sn[4];
  int tid = threadIdx.x, lane = tid & 63, wv = tid >> 6;

  // each block redundantly counts the full label histogram (L2-resident, deterministic)
  int c0 = 0, c1 = 0;
  for (int i = tid; i < B_N; i += 256) {
    if (mask[i] != 0) { if (labels[i] == 0) c0++; else c1++; }
  }
  #pragma unroll
  for (int m = 1; m < 64; m <<= 1) { c0 += __shfl_xor(c0, m); c1 += __shfl_xor(c1, m); }
  if (lane == 0) { sc0[wv] = c0; sc1[wv] = c1; }
  __syncthreads();
  int cnt0 = sc0[0] + sc0[1] + sc0[2] + sc0[3];
  int cnt1 = sc1[0] + sc1[1] + sc1[2] + sc1[3];

  // one row per thread
  int r = blockIdx.x * 256 + tid;
  float s0 = 0.f, tt = 0.f;
  for (int s = 0; s < NS; ++s) {
    float2 v = SW[(size_t)s * B_N + r];
    s0 += v.x; tt += v.y;
  }
  int lb = labels[r];
  float pos = (lb == 0) ? s0 : (tt - s0);
  int cnt = (lb == 0) ? cnt0 : cnt1;
  float tot = 0.f, nv = 0.f;
  if (mask[r] != 0 && cnt > 1) {
    // den = pos + neg = tt (diag already excluded); loss = log(den+EPS) - log(pos)
    tot = logf(tt + 1e-8f) - logf(pos);
    nv = 1.f;
  }
  #pragma unroll
  for (int m = 1; m < 64; m <<= 1) { tot += __shfl_xor(tot, m); nv += __shfl_xor(nv, m); }
  if (lane == 0) { st[wv] = tot; sn[wv] = nv; }
  __syncthreads();
  if (tid == 0) {
    partial[blockIdx.x] = make_float2(st[0] + st[1] + st[2] + st[3],
                                      sn[0] + sn[1] + sn[2] + sn[3]);
  }
}

// ---------------- kernel 3b: final deterministic reduce (one wave)
__global__ __launch_bounds__(64) void loss_final(
    const float2* __restrict__ partial, int nb, float* __restrict__ out)
{
  int lane = threadIdx.x;
  float t = 0.f, n = 0.f;
  for (int i = lane; i < nb; i += 64) {
    float2 v = partial[i];
    t += v.x; n += v.y;
  }
  #pragma unroll
  for (int m = 1; m < 64; m <<= 1) { t += __shfl_xor(t, m); n += __shfl_xor(n, m); }
  if (lane == 0) out[0] = (n > 0.f) ? t / fmaxf(n, 1.f) : 0.f;
}

extern "C" void kernel_launch(void* const* d_in, const int* in_sizes, int n_in,
                              void* d_out, int out_size, void* d_ws, size_t ws_size,
                              hipStream_t stream)
{
  const float* E = (const float*)d_in[0];
  const int* labels = (const int*)d_in[1];
  const int* mask = (const int*)d_in[2];

  char* ws = (char*)d_ws;
  __hip_bfloat16* Ebf = (__hip_bfloat16*)ws;                       // 4 MB
  float2* W = (float2*)(ws + (size_t)B_N * D_K * 2);               // 128 KB
  float2* SW = (float2*)(ws + (size_t)B_N * D_K * 2 + (size_t)B_N * 8);
  size_t base = (size_t)B_N * D_K * 2 + (size_t)B_N * 8;

  int NS = 16;  // col splits; 16 -> grid 1024 blocks; shrink if workspace tight
  while (NS > 1 && base + (size_t)NS * B_N * 8 + 1024 > ws_size) NS >>= 1;
  int cps = B_N / NS;
  float2* partial = (float2*)(ws + base + (size_t)NS * B_N * 8);

  prep_kernel<<<1024, 256, 0, stream>>>(E, labels, mask, Ebf, W);
  dim3 g2(B_N / 256, NS);
  gemm_kernel<<<g2, 256, 0, stream>>>(Ebf, W, SW, cps);
  loss_part<<<B_N / 256, 256, 0, stream>>>(labels, mask, SW, NS, partial);
  loss_final<<<1, 64, 0, stream>>>(partial, B_N / 256, (float*)d_out);
}

// Round 4
// 135.737 us; speedup vs baseline: 2.2250x; 2.2250x over previous
//
#include <hip/hip_runtime.h>
#include <hip/hip_bf16.h>

#define B_N 16384
#define D_K 128
#define BM 128           // rows per block (4 waves x 32 rows)

typedef __bf16 bf16x8 __attribute__((ext_vector_type(8)));
typedef float f32x4 __attribute__((ext_vector_type(4)));
typedef float f32x2 __attribute__((ext_vector_type(2)));

#if defined(__has_builtin)
#if __has_builtin(__builtin_amdgcn_exp2f)
#define EXP2F(x) __builtin_amdgcn_exp2f(x)
#else
#define EXP2F(x) exp2f(x)
#endif
#else
#define EXP2F(x) exp2f(x)
#endif

__device__ __forceinline__ void gload_lds16(const void* g, void* l) {
  __builtin_amdgcn_global_load_lds(
      (const __attribute__((address_space(1))) unsigned int*)g,
      (__attribute__((address_space(3))) unsigned int*)l, 16, 0, 0);
}

// ---------------- kernel 1: normalize rows, prescale by sqrt(1/(T*ln2)), build col weights
__global__ __launch_bounds__(256) void prep_kernel(
    const float* __restrict__ E, const int* __restrict__ labels,
    const int* __restrict__ mask, __hip_bfloat16* __restrict__ Ebf,
    float2* __restrict__ W)
{
  int tid = threadIdx.x;
  int gtid = blockIdx.x * 256 + tid;
  if (gtid < B_N) {
    int lb = labels[gtid];
    float wm = (mask[gtid] != 0) ? 1.0f : 0.0f;
    W[gtid] = make_float2((lb == 0) ? wm : 0.0f, wm);
  }
  int lane = tid & 63;
  int wid = gtid >> 6;  // 4096 waves total (grid 1024 x 256) -> 4 rows/wave
  const float2* E2 = (const float2*)E;
  __hip_bfloat162* O2 = (__hip_bfloat162*)Ebf;
  for (int row = wid; row < B_N; row += 4096) {
    float2 v = E2[row * 64 + lane];
    float ss = v.x * v.x + v.y * v.y;
    #pragma unroll
    for (int m = 1; m < 64; m <<= 1) ss += __shfl_xor(ss, m);
    // sqrt(14.426950408889634) = sqrt(1/(0.1*ln2)); folded into both operands
    float sc = 3.7982826f / fmaxf(sqrtf(ss), 1e-12f);
    __hip_bfloat162 h;
    h.x = __float2bfloat16(v.x * sc);
    h.y = __float2bfloat16(v.y * sc);
    O2[row * 64 + lane] = h;
  }
}

// ---------------- kernel 2: fused Gram + exp + masked row-sum
// 64-col double-buffered tiles, T3 2-phase schedule (stage next -> compute cur -> vmcnt(0) -> barrier)
// 32 rows/wave geometry: a[2][4]=32 VGPR + acc[2][4]=16 -> live state fits the 170-reg
// unified budget of (256,3). [64 rows/wave needed >170 and spilled: rounds 1 & 3.]
template<bool DIAG>
__device__ __forceinline__ void tile_compute(
    const char* lds, const bf16x8 a[2][4],
    const float2* __restrict__ W, int C0, int lane, int WR0,
    f32x2 acc[2][4])
{
  const int l15 = lane & 15, lg = lane >> 4, l7 = lane & 7;
  #pragma unroll
  for (int nf = 0; nf < 4; ++nf) {   // 4 x 16 = 64 cols
    int col = nf * 16 + l15;
    int colg = C0 + col;
    f32x2 wv = *(const f32x2*)&W[colg];  // (label0 weight, total weight)
    bf16x8 b[4];
    #pragma unroll
    for (int kk = 0; kk < 4; ++kk) {
      // XOR-swizzled chunk address (matches swizzled staging source)
      int addr = col * 256 + (((kk * 4 + lg) ^ l7) << 4);
      b[kk] = *(const bf16x8*)(lds + addr);
    }
    #pragma unroll
    for (int mf = 0; mf < 2; ++mf) {
      f32x4 c = {0.f, 0.f, 0.f, 0.f};
      #pragma unroll
      for (int kk = 0; kk < 4; ++kk)
        c = __builtin_amdgcn_mfma_f32_16x16x32_bf16(a[mf][kk], b[kk], c, 0, 0, 0);
      #pragma unroll
      for (int r = 0; r < 4; ++r) {
        float p = EXP2F(c[r]);       // exp(sim/T), scale folded into operands
        if (DIAG) {
          int rowg = WR0 + mf * 16 + lg * 4 + r;  // verified C/D layout
          p = (rowg == colg) ? 0.0f : p;
        }
        // packed FMA: one v_pk_fma_f32 updates (label-0 sum, total sum)
        acc[mf][r] += wv * p;
      }
    }
  }
}

// launch_bounds 2nd arg = min waves/EU; budget = UNIFIED VGPR+AGPR (512-reg/SIMD pool).
// 64-row/wave: live >170 -> (256,3)/(256,4) spilled (FETCH 17MB->320MB/1.8GB).
// 32-row/wave: live ~110-140 -> fits 170 -> guaranteed 3 waves/SIMD.
__global__ __launch_bounds__(256, 3) void gemm_kernel(
    const __hip_bfloat16* __restrict__ Ebf, const float2* __restrict__ W,
    float2* __restrict__ SW, int colsPerSplit)
{
  __shared__ alignas(16) char tile[32768];  // 2 buffers x (64 cols x 128 K x bf16)
  const int tid = threadIdx.x;
  const int lane = tid & 63;
  const int w = tid >> 6;
  const int R0 = blockIdx.x * BM;
  const int WR0 = R0 + w * 32;   // 32 rows per wave
  const int l15 = lane & 15, lg = lane >> 4;

  // A fragments: 2 m-frags x 4 k-steps, held in VGPRs for the whole col loop
  bf16x8 a[2][4];
  #pragma unroll
  for (int mf = 0; mf < 2; ++mf) {
    #pragma unroll
    for (int kk = 0; kk < 4; ++kk) {
      int row = WR0 + mf * 16 + l15;
      a[mf][kk] = *(const bf16x8*)(Ebf + (size_t)row * D_K + kk * 32 + lg * 8);
    }
  }

  // staging offsets: linear LDS dest, swizzle applied to the GLOBAL source (m173 pattern)
  int goff[4], loff[4];
  #pragma unroll
  for (int i = 0; i < 4; ++i) {
    int q = i * 4 + w;            // 1KB chunk-group id 0..15 (16KB tile)
    int col = q * 4 + lg;         // tile-local col this lane feeds (0..63)
    int c = l15 ^ (col & 7);      // inverse-swizzled 16B chunk within the 256B row
    goff[i] = col * D_K + c * 8;  // bf16 elements
    loff[i] = q * 1024;           // wave-uniform LDS base (bytes)
  }

  f32x2 acc[2][4] = {};
  const int colBase = blockIdx.y * colsPerSplit;
  const int nt = colsPerSplit >> 6;

  // prologue: stage tile 0, drain, rendezvous
  {
    const __hip_bfloat16* src = Ebf + (size_t)colBase * D_K;
    #pragma unroll
    for (int i = 0; i < 4; ++i) gload_lds16(src + goff[i], tile + loff[i]);
    asm volatile("s_waitcnt vmcnt(0)" ::: "memory");
    __builtin_amdgcn_s_barrier();
  }

  int cur = 0;
  for (int t = 0; t < nt; ++t) {
    if (t + 1 < nt) {   // block-uniform branch: prefetch next tile into the other buffer
      const __hip_bfloat16* src = Ebf + (size_t)(colBase + (t + 1) * 64) * D_K;
      char* dst = tile + ((cur ^ 1) << 14);
      #pragma unroll
      for (int i = 0; i < 4; ++i) gload_lds16(src + goff[i], dst + loff[i]);
    }
    const int C0 = colBase + t * 64;
    const char* lds = tile + (cur << 14);
    const bool diag = (C0 < R0 + BM) && (C0 + 64 > R0);
    if (diag) tile_compute<true >(lds, a, W, C0, lane, WR0, acc);
    else      tile_compute<false>(lds, a, W, C0, lane, WR0, acc);
    // loads for tile t+1 were issued BEFORE compute: this drain is latency-hidden
    asm volatile("s_waitcnt vmcnt(0)" ::: "memory");
    __builtin_amdgcn_s_barrier();
    cur ^= 1;
  }

  // reduce the 16 lanes (same row-group, different col subsets), then store
  #pragma unroll
  for (int mf = 0; mf < 2; ++mf) {
    #pragma unroll
    for (int r = 0; r < 4; ++r) {
      float s0 = acc[mf][r].x, tt = acc[mf][r].y;
      #pragma unroll
      for (int m = 1; m < 16; m <<= 1) {
        s0 += __shfl_xor(s0, m);
        tt += __shfl_xor(tt, m);
      }
      if (l15 == 0) {
        int rowg = WR0 + mf * 16 + lg * 4 + r;
        SW[(size_t)blockIdx.y * B_N + rowg] = make_float2(s0, tt);
      }
    }
  }
}

// ---------------- kernel 3a: per-row loss, 64 blocks, deterministic partials
__global__ __launch_bounds__(256) void loss_part(
    const int* __restrict__ labels, const int* __restrict__ mask,
    const float2* __restrict__ SW, int NS, float2* __restrict__ partial)
{
  __shared__ int sc0[4], sc1[4];
  __shared__ float st[4], sn[4];
  int tid = threadIdx.x, lane = tid & 63, wv = tid >> 6;

  // each block redundantly counts the full label histogram (L2-resident, deterministic)
  int c0 = 0, c1 = 0;
  for (int i = tid; i < B_N; i += 256) {
    if (mask[i] != 0) { if (labels[i] == 0) c0++; else c1++; }
  }
  #pragma unroll
  for (int m = 1; m < 64; m <<= 1) { c0 += __shfl_xor(c0, m); c1 += __shfl_xor(c1, m); }
  if (lane == 0) { sc0[wv] = c0; sc1[wv] = c1; }
  __syncthreads();
  int cnt0 = sc0[0] + sc0[1] + sc0[2] + sc0[3];
  int cnt1 = sc1[0] + sc1[1] + sc1[2] + sc1[3];

  // one row per thread
  int r = blockIdx.x * 256 + tid;
  float s0 = 0.f, tt = 0.f;
  for (int s = 0; s < NS; ++s) {
    float2 v = SW[(size_t)s * B_N + r];
    s0 += v.x; tt += v.y;
  }
  int lb = labels[r];
  float pos = (lb == 0) ? s0 : (tt - s0);
  int cnt = (lb == 0) ? cnt0 : cnt1;
  float tot = 0.f, nv = 0.f;
  if (mask[r] != 0 && cnt > 1) {
    // den = pos + neg = tt (diag already excluded); loss = log(den+EPS) - log(pos)
    tot = logf(tt + 1e-8f) - logf(pos);
    nv = 1.f;
  }
  #pragma unroll
  for (int m = 1; m < 64; m <<= 1) { tot += __shfl_xor(tot, m); nv += __shfl_xor(nv, m); }
  if (lane == 0) { st[wv] = tot; sn[wv] = nv; }
  __syncthreads();
  if (tid == 0) {
    partial[blockIdx.x] = make_float2(st[0] + st[1] + st[2] + st[3],
                                      sn[0] + sn[1] + sn[2] + sn[3]);
  }
}

// ---------------- kernel 3b: final deterministic reduce (one wave)
__global__ __launch_bounds__(64) void loss_final(
    const float2* __restrict__ partial, int nb, float* __restrict__ out)
{
  int lane = threadIdx.x;
  float t = 0.f, n = 0.f;
  for (int i = lane; i < nb; i += 64) {
    float2 v = partial[i];
    t += v.x; n += v.y;
  }
  #pragma unroll
  for (int m = 1; m < 64; m <<= 1) { t += __shfl_xor(t, m); n += __shfl_xor(n, m); }
  if (lane == 0) out[0] = (n > 0.f) ? t / fmaxf(n, 1.f) : 0.f;
}

extern "C" void kernel_launch(void* const* d_in, const int* in_sizes, int n_in,
                              void* d_out, int out_size, void* d_ws, size_t ws_size,
                              hipStream_t stream)
{
  const float* E = (const float*)d_in[0];
  const int* labels = (const int*)d_in[1];
  const int* mask = (const int*)d_in[2];

  char* ws = (char*)d_ws;
  __hip_bfloat16* Ebf = (__hip_bfloat16*)ws;                       // 4 MB
  float2* W = (float2*)(ws + (size_t)B_N * D_K * 2);               // 128 KB
  float2* SW = (float2*)(ws + (size_t)B_N * D_K * 2 + (size_t)B_N * 8);
  size_t base = (size_t)B_N * D_K * 2 + (size_t)B_N * 8;

  int NS = 16;  // col splits; shrink if workspace tight
  while (NS > 1 && base + (size_t)NS * B_N * 8 + 1024 > ws_size) NS >>= 1;
  int cps = B_N / NS;
  float2* partial = (float2*)(ws + base + (size_t)NS * B_N * 8);

  prep_kernel<<<1024, 256, 0, stream>>>(E, labels, mask, Ebf, W);
  dim3 g2(B_N / BM, NS);   // (128, 16) = 2048 blocks
  gemm_kernel<<<g2, 256, 0, stream>>>(Ebf, W, SW, cps);
  loss_part<<<B_N / 256, 256, 0, stream>>>(labels, mask, SW, NS, partial);
  loss_final<<<1, 64, 0, stream>>>(partial, B_N / 256, (float*)d_out);
}

// Round 5
// 130.617 us; speedup vs baseline: 2.3122x; 1.0392x over previous
//
#include <hip/hip_runtime.h>
#include <hip/hip_bf16.h>

#define B_N 16384
#define D_K 128
#define BM 256           // rows per block (4 waves x 64 rows) -- round-2 local-optimum geometry

typedef __bf16 bf16x8 __attribute__((ext_vector_type(8)));
typedef float f32x4 __attribute__((ext_vector_type(4)));
typedef float f32x2 __attribute__((ext_vector_type(2)));

#if defined(__has_builtin)
#if __has_builtin(__builtin_amdgcn_exp2f)
#define EXP2F(x) __builtin_amdgcn_exp2f(x)
#else
#define EXP2F(x) exp2f(x)
#endif
#else
#define EXP2F(x) exp2f(x)
#endif

__device__ __forceinline__ void gload_lds16(const void* g, void* l) {
  __builtin_amdgcn_global_load_lds(
      (const __attribute__((address_space(1))) unsigned int*)g,
      (__attribute__((address_space(3))) unsigned int*)l, 16, 0, 0);
}

// ---------------- kernel 1: normalize rows, prescale by sqrt(1/(T*ln2)), build col weights
__global__ __launch_bounds__(256) void prep_kernel(
    const float* __restrict__ E, const int* __restrict__ labels,
    const int* __restrict__ mask, __hip_bfloat16* __restrict__ Ebf,
    float2* __restrict__ W)
{
  int tid = threadIdx.x;
  int gtid = blockIdx.x * 256 + tid;
  if (gtid < B_N) {
    int lb = labels[gtid];
    float wm = (mask[gtid] != 0) ? 1.0f : 0.0f;
    W[gtid] = make_float2((lb == 0) ? wm : 0.0f, wm);
  }
  int lane = tid & 63;
  int wid = gtid >> 6;  // 4096 waves total (grid 1024 x 256) -> 4 rows/wave
  const float2* E2 = (const float2*)E;
  __hip_bfloat162* O2 = (__hip_bfloat162*)Ebf;
  for (int row = wid; row < B_N; row += 4096) {
    float2 v = E2[row * 64 + lane];
    float ss = v.x * v.x + v.y * v.y;
    #pragma unroll
    for (int m = 1; m < 64; m <<= 1) ss += __shfl_xor(ss, m);
    // sqrt(14.426950408889634) = sqrt(1/(0.1*ln2)); folded into both operands
    float sc = 3.7982826f / fmaxf(sqrtf(ss), 1e-12f);
    __hip_bfloat162 h;
    h.x = __float2bfloat16(v.x * sc);
    h.y = __float2bfloat16(v.y * sc);
    O2[row * 64 + lane] = h;
  }
}

// ---------------- kernel 2: fused Gram + exp + masked row-sum
// 64-col tiles in a 3-buffer LDS ring; 1 barrier + counted vmcnt(4) per tile (T3/T4);
// W slice staged to LDS once per block; setprio around the MFMA cluster (T5).
template<bool DIAG>
__device__ __forceinline__ void tile_compute(
    const char* lds, const char* ldsW, const bf16x8 a[4][4],
    int C0loc, int colBase, int lane, int WR0,
    f32x2 acc[4][4])
{
  const int l15 = lane & 15, lg = lane >> 4, l7 = lane & 7;
  #pragma unroll
  for (int nf = 0; nf < 4; ++nf) {   // 4 x 16 = 64 cols
    int col = nf * 16 + l15;
    int colg = colBase + C0loc + col;
    f32x2 wv = *(const f32x2*)(ldsW + ((C0loc + col) << 3));  // 4-lane broadcast, conflict-free
    bf16x8 b[4];
    #pragma unroll
    for (int kk = 0; kk < 4; ++kk) {
      // XOR-swizzled chunk address (matches swizzled staging source)
      int addr = col * 256 + (((kk * 4 + lg) ^ l7) << 4);
      b[kk] = *(const bf16x8*)(lds + addr);
    }
    // MFMA cluster first (c[4] in regs), then the VALU epilogue -- lets setprio
    // arbitrate between MFMA-issuing and VALU/stage-issuing waves.
    f32x4 c[4];
    __builtin_amdgcn_s_setprio(1);
    #pragma unroll
    for (int mf = 0; mf < 4; ++mf) {
      f32x4 t = {0.f, 0.f, 0.f, 0.f};
      #pragma unroll
      for (int kk = 0; kk < 4; ++kk)
        t = __builtin_amdgcn_mfma_f32_16x16x32_bf16(a[mf][kk], b[kk], t, 0, 0, 0);
      c[mf] = t;
    }
    __builtin_amdgcn_s_setprio(0);
    #pragma unroll
    for (int mf = 0; mf < 4; ++mf) {
      #pragma unroll
      for (int r = 0; r < 4; ++r) {
        float p = EXP2F(c[mf][r]);   // exp(sim/T), scale folded into operands
        if (DIAG) {
          int rowg = WR0 + mf * 16 + lg * 4 + r;  // verified C/D layout
          p = (rowg == colg) ? 0.0f : p;
        }
        acc[mf][r] += wv * p;        // v_pk_fma_f32: (label-0 sum, total sum)
      }
    }
  }
}

// (256,2) = 256-reg unified budget; live state ~160 regs. (256,3)/(256,4) spill
// catastrophically on this geometry (rounds 1/3: FETCH 17MB -> 0.3-1.8GB).
__global__ __launch_bounds__(256, 2) void gemm_kernel(
    const __hip_bfloat16* __restrict__ Ebf, const float2* __restrict__ W,
    float2* __restrict__ SW, int colsPerSplit)
{
  // 16 KB W slice (supports cps up to 2048) + 3 x 16 KB tile ring = 64 KB
  __shared__ alignas(16) char smem[65536];
  char* ldsW  = smem;
  char* tiles = smem + 16384;

  const int tid = threadIdx.x;
  const int lane = tid & 63;
  const int w = tid >> 6;
  const int R0 = blockIdx.x * BM;
  const int WR0 = R0 + w * 64;   // 64 rows per wave
  const int l15 = lane & 15, lg = lane >> 4;

  // A fragments: 4 m-frags x 4 k-steps, held in VGPRs for the whole col loop
  bf16x8 a[4][4];
  #pragma unroll
  for (int mf = 0; mf < 4; ++mf) {
    #pragma unroll
    for (int kk = 0; kk < 4; ++kk) {
      int row = WR0 + mf * 16 + l15;
      a[mf][kk] = *(const bf16x8*)(Ebf + (size_t)row * D_K + kk * 32 + lg * 8);
    }
  }

  // staging offsets: linear LDS dest, swizzle applied to the GLOBAL source (m173 pattern)
  int goff[4], loff[4];
  #pragma unroll
  for (int i = 0; i < 4; ++i) {
    int q = i * 4 + w;            // 1KB chunk-group id 0..15 (16KB tile)
    int col = q * 4 + lg;         // tile-local col this lane feeds (0..63)
    int c = l15 ^ (col & 7);      // inverse-swizzled 16B chunk within the 256B row
    goff[i] = col * D_K + c * 8;  // bf16 elements
    loff[i] = q * 1024;           // wave-uniform LDS base (bytes)
  }

  f32x2 acc[4][4] = {};
  const int colBase = blockIdx.y * colsPerSplit;
  const int nt = colsPerSplit >> 6;

  // ---- stage W slice into LDS (gload_lds; retired by the first vmcnt(4) as oldest)
  {
    const char* wsrc = (const char*)(W + colBase);
    int nW = colsPerSplit >> 9;   // 16B-chunks: 512 cols per i across 4 waves
    for (int i = 0; i < nW; ++i)
      gload_lds16(wsrc + (((i * 4 + w) * 64 + lane) << 4), ldsW + ((i * 4 + w) << 10));
  }

  // ---- prologue: stage tiles 0 and 1 (ring depth 2 in flight)
  {
    const __hip_bfloat16* src0 = Ebf + (size_t)colBase * D_K;
    #pragma unroll
    for (int i = 0; i < 4; ++i) gload_lds16(src0 + goff[i], tiles + loff[i]);
    if (nt > 1) {
      const __hip_bfloat16* src1 = Ebf + (size_t)(colBase + 64) * D_K;
      #pragma unroll
      for (int i = 0; i < 4; ++i) gload_lds16(src1 + goff[i], tiles + 16384 + loff[i]);
    }
  }

  int bufOff = 0;  // current ring-buffer byte offset: 0 / 16384 / 32768
  for (int t = 0; t < nt; ++t) {
    // counted wait: tile-t loads (and, at t=0, the W loads) are the oldest outstanding
    if (t + 1 < nt) asm volatile("s_waitcnt vmcnt(4)" ::: "memory");
    else            asm volatile("s_waitcnt vmcnt(0)" ::: "memory");
    __builtin_amdgcn_s_barrier();              // all waves' tile-t chunks complete
    asm volatile("" ::: "memory");             // pin LDS reads below the barrier
    if (t + 2 < nt) {                          // overwrites buf (t-1)%3: all compute(t-1) done
      int nb = bufOff + 32768; if (nb >= 49152) nb -= 49152;
      const __hip_bfloat16* src = Ebf + (size_t)(colBase + ((t + 2) << 6)) * D_K;
      #pragma unroll
      for (int i = 0; i < 4; ++i) gload_lds16(src + goff[i], tiles + nb + loff[i]);
    }
    const int C0loc = t << 6;
    const int Cg = colBase + C0loc;
    const bool diag = (Cg < R0 + BM) && (Cg + 64 > R0);
    if (diag) tile_compute<true >(tiles + bufOff, ldsW, a, C0loc, colBase, lane, WR0, acc);
    else      tile_compute<false>(tiles + bufOff, ldsW, a, C0loc, colBase, lane, WR0, acc);
    bufOff += 16384; if (bufOff == 49152) bufOff = 0;
  }

  // reduce the 16 lanes (same row-group, different col subsets), then store
  #pragma unroll
  for (int mf = 0; mf < 4; ++mf) {
    #pragma unroll
    for (int r = 0; r < 4; ++r) {
      float s0 = acc[mf][r].x, tt = acc[mf][r].y;
      #pragma unroll
      for (int m = 1; m < 16; m <<= 1) {
        s0 += __shfl_xor(s0, m);
        tt += __shfl_xor(tt, m);
      }
      if (l15 == 0) {
        int rowg = WR0 + mf * 16 + lg * 4 + r;
        SW[(size_t)blockIdx.y * B_N + rowg] = make_float2(s0, tt);
      }
    }
  }
}

// ---------------- kernel 3a: per-row loss, 64 blocks, deterministic partials
__global__ __launch_bounds__(256) void loss_part(
    const int* __restrict__ labels, const int* __restrict__ mask,
    const float2* __restrict__ SW, int NS, float2* __restrict__ partial)
{
  __shared__ int sc0[4], sc1[4];
  __shared__ float st[4], sn[4];
  int tid = threadIdx.x, lane = tid & 63, wv = tid >> 6;

  // each block redundantly counts the full label histogram (L2-resident, deterministic)
  int c0 = 0, c1 = 0;
  for (int i = tid; i < B_N; i += 256) {
    if (mask[i] != 0) { if (labels[i] == 0) c0++; else c1++; }
  }
  #pragma unroll
  for (int m = 1; m < 64; m <<= 1) { c0 += __shfl_xor(c0, m); c1 += __shfl_xor(c1, m); }
  if (lane == 0) { sc0[wv] = c0; sc1[wv] = c1; }
  __syncthreads();
  int cnt0 = sc0[0] + sc0[1] + sc0[2] + sc0[3];
  int cnt1 = sc1[0] + sc1[1] + sc1[2] + sc1[3];

  // one row per thread
  int r = blockIdx.x * 256 + tid;
  float s0 = 0.f, tt = 0.f;
  for (int s = 0; s < NS; ++s) {
    float2 v = SW[(size_t)s * B_N + r];
    s0 += v.x; tt += v.y;
  }
  int lb = labels[r];
  float pos = (lb == 0) ? s0 : (tt - s0);
  int cnt = (lb == 0) ? cnt0 : cnt1;
  float tot = 0.f, nv = 0.f;
  if (mask[r] != 0 && cnt > 1) {
    // den = pos + neg = tt (diag already excluded); loss = log(den+EPS) - log(pos)
    tot = logf(tt + 1e-8f) - logf(pos);
    nv = 1.f;
  }
  #pragma unroll
  for (int m = 1; m < 64; m <<= 1) { tot += __shfl_xor(tot, m); nv += __shfl_xor(nv, m); }
  if (lane == 0) { st[wv] = tot; sn[wv] = nv; }
  __syncthreads();
  if (tid == 0) {
    partial[blockIdx.x] = make_float2(st[0] + st[1] + st[2] + st[3],
                                      sn[0] + sn[1] + sn[2] + sn[3]);
  }
}

// ---------------- kernel 3b: final deterministic reduce (one wave)
__global__ __launch_bounds__(64) void loss_final(
    const float2* __restrict__ partial, int nb, float* __restrict__ out)
{
  int lane = threadIdx.x;
  float t = 0.f, n = 0.f;
  for (int i = lane; i < nb; i += 64) {
    float2 v = partial[i];
    t += v.x; n += v.y;
  }
  #pragma unroll
  for (int m = 1; m < 64; m <<= 1) { t += __shfl_xor(t, m); n += __shfl_xor(n, m); }
  if (lane == 0) out[0] = (n > 0.f) ? t / fmaxf(n, 1.f) : 0.f;
}

extern "C" void kernel_launch(void* const* d_in, const int* in_sizes, int n_in,
                              void* d_out, int out_size, void* d_ws, size_t ws_size,
                              hipStream_t stream)
{
  const float* E = (const float*)d_in[0];
  const int* labels = (const int*)d_in[1];
  const int* mask = (const int*)d_in[2];

  char* ws = (char*)d_ws;
  __hip_bfloat16* Ebf = (__hip_bfloat16*)ws;                       // 4 MB
  float2* W = (float2*)(ws + (size_t)B_N * D_K * 2);               // 128 KB
  float2* SW = (float2*)(ws + (size_t)B_N * D_K * 2 + (size_t)B_N * 8);
  size_t base = (size_t)B_N * D_K * 2 + (size_t)B_N * 8;

  int NS = 16;  // col splits; floor 8 (W LDS slice sized for cps <= 2048)
  while (NS > 8 && base + (size_t)NS * B_N * 8 + 1024 > ws_size) NS >>= 1;
  int cps = B_N / NS;
  float2* partial = (float2*)(ws + base + (size_t)NS * B_N * 8);

  prep_kernel<<<1024, 256, 0, stream>>>(E, labels, mask, Ebf, W);
  dim3 g2(B_N / BM, NS);   // (64, 16) = 1024 blocks, 2 blocks/CU
  gemm_kernel<<<g2, 256, 0, stream>>>(Ebf, W, SW, cps);
  loss_part<<<B_N / 256, 256, 0, stream>>>(labels, mask, SW, NS, partial);
  loss_final<<<1, 64, 0, stream>>>(partial, B_N / 256, (float*)d_out);
}